// Round 1
// baseline (86.846 us; speedup 1.0000x reference)
//
#include <hip/hip_runtime.h>

#define NPTS    6144
#define DIM     32
#define NB      2
#define NCELL   1000          // 10x10x10, cell edge = 0.03 = radius
#define R2      0.0009f
#define NWAVES  4
#define BLOCK   (NWAVES * 64)
#define LEAFBIT 8192
#define PPT     6             // points per thread in build_cells (6144/1024)
#define NBCAP   128           // max neighbors kept per point (obs ~13)
#define COPYBLK 64            // extra blocks in K1 that bulk-copy emb->out

__device__ __forceinline__ int cellof(float x) {
    int c = (int)(x * (10.0f / 0.3f));
    return min(max(c, 0), 9);
}

// ---- ws layout (ints) ----
#define WS_LEAF   0
#define WS_CSTART 4
#define WS_SORTED 2008   // float4 [NB][NPTS], byte 8032 (16B aligned)

// K1: blocks 0..NB-1: one block per batch, LDS histogram -> shfl scan ->
// LDS-cursor scatter (unchanged). Blocks NB..NB+COPYBLK-1: bulk float4 copy
// emb->out on otherwise-idle CUs, hidden under the build blocks' runtime.
// After K1, out == emb everywhere; refine only overwrites refined rows.
__global__ __launch_bounds__(1024)
void build_cells(const float* __restrict__ points, const int* __restrict__ leaf,
                 const float* __restrict__ emb, float* __restrict__ out,
                 int* __restrict__ ws)
{
    __shared__ int s_hist[1024];
    __shared__ int s_cursor[1024];
    __shared__ int s_wsum[16];
    __shared__ int s_leaf;

    if (blockIdx.x >= NB) {                    // ---- copy blocks ----
        const int cb = blockIdx.x - NB;
        const float4* src = (const float4*)emb;
        float4*       dst = (float4*)out;
        const int total = NB * NPTS * (DIM / 4);          // 98304
        for (int i = cb * 1024 + threadIdx.x; i < total; i += COPYBLK * 1024)
            dst[i] = src[i];
        return;
    }

    const int t = threadIdx.x;
    const int b = blockIdx.x;
    const int w = t >> 6, lane = t & 63;

    s_hist[t] = 0;
    if (t == 0) s_leaf = 0;

    float px[PPT], py[PPT], pz[PPT];
    int   pc[PPT], pw[PPT];

    __syncthreads();

    int lc = 0;
    #pragma unroll
    for (int r = 0; r < PPT; ++r) {
        const int i  = r * 1024 + t;
        const int gi = b * NPTS + i;
        px[r] = points[gi * 3 + 0];
        py[r] = points[gi * 3 + 1];
        pz[r] = points[gi * 3 + 2];
        const int lf = leaf[gi] > 0 ? 1 : 0;
        lc += lf;
        pc[r] = (cellof(pz[r]) * 10 + cellof(py[r])) * 10 + cellof(px[r]);
        pw[r] = i + (lf ? LEAFBIT : 0);
        atomicAdd(&s_hist[pc[r]], 1);
    }
    #pragma unroll
    for (int off = 32; off > 0; off >>= 1) lc += __shfl_down(lc, off);
    if (lane == 0) atomicAdd(&s_leaf, lc);
    __syncthreads();

    const int v = s_hist[t];
    int x = v;
    #pragma unroll
    for (int off = 1; off < 64; off <<= 1) {
        const int y = __shfl_up(x, off);
        if (lane >= off) x += y;
    }
    if (lane == 63) s_wsum[w] = x;
    __syncthreads();
    if (t < 16) {
        int wv = s_wsum[t];
        #pragma unroll
        for (int off = 1; off < 16; off <<= 1) {
            const int y = __shfl_up(wv, off);
            if (t >= off) wv += y;
        }
        s_wsum[t] = wv;
    }
    __syncthreads();
    const int incl = x + (w > 0 ? s_wsum[w - 1] : 0);
    s_cursor[t] = incl - v;

    if (t < NCELL) ws[WS_CSTART + b * (NCELL + 1) + t + 1] = incl;
    if (t == 0) {
        ws[WS_CSTART + b * (NCELL + 1)] = 0;
        ws[WS_LEAF + b] = s_leaf;
    }
    __syncthreads();

    float4* sorted = (float4*)(ws + WS_SORTED) + (size_t)b * NPTS;
    #pragma unroll
    for (int r = 0; r < PPT; ++r) {
        const int pos = atomicAdd(&s_cursor[pc[r]], 1);
        sorted[pos] = make_float4(px[r], py[r], pz[r], (float)pw[r]);
    }
}

// K2: wave per point. out already holds emb (K1 copy blocks), so every
// non-refined wave exits with ZERO memory writes. Leaf path uses all 64
// lanes end-to-end:
//   - e-norm: shfl_xor tree (was 32-long serial LDS loop)
//   - Phase B: 2 lanes per hit (4 float4 loads + 16 FMA each, shfl combine)
//   - survivor mean + both MLP layers: k-range split across lane halves,
//     one shfl_xor(32) combine -> serial chains halved
__global__ __launch_bounds__(BLOCK)
void refine(const float* __restrict__ emb,
            const float* __restrict__ W1, const float* __restrict__ b1,
            const float* __restrict__ W2, const float* __restrict__ b2,
            const int* __restrict__ ws, float* __restrict__ out)
{
    __shared__ __align__(16) float s_ei[NWAVES][DIM];
    __shared__ float s_mean[NWAVES][DIM];
    __shared__ float s_h[NWAVES][DIM];
    __shared__ int   s_nb[NWAVES][NBCAP];
    __shared__ int   s_sv[NWAVES][NBCAP];

    const int tid  = threadIdx.x;
    const int wid  = tid >> 6;
    const int lane = tid & 63;
    const int s    = blockIdx.x * NWAVES + wid;
    const int b    = s / NPTS;
    const int slot = s - b * NPTS;

    if (ws[WS_LEAF + b] < 10) return;            // batch-uniform: out = emb done

    const float4* srt  = (const float4*)(ws + WS_SORTED) + (size_t)b * NPTS;
    const int*    cst  = ws + WS_CSTART + b * (NCELL + 1);
    const float*  embB = emb + (size_t)b * NPTS * DIM;

    const float4 P  = srt[slot];
    const int    iw = (int)P.w;
    if (!(iw & LEAFBIT)) return;                 // non-leaf: out = emb done
    const int io = iw & (LEAFBIT - 1);

    // ---- load center embedding, norm via shfl tree ----
    const float* ei = embB + (size_t)io * DIM;
    float ev = 0.0f;
    if (lane < DIM) { ev = ei[lane]; s_ei[wid][lane] = ev; }
    float nsq = ev * ev;
    #pragma unroll
    for (int off = 16; off > 0; off >>= 1) nsq += __shfl_xor(nsq, off);
    const float ni2 = __shfl(nsq, 0);
    const float rni = 1.0f / fmaxf(sqrtf(ni2), 1e-8f);

    const int cx = cellof(P.x), cy = cellof(P.y), cz = cellof(P.z);

    int begv = 0, lenv = 0;
    if (lane < 9) {
        const int z = cz + lane / 3 - 1;
        const int y = cy + lane % 3 - 1;
        if ((unsigned)z <= 9u && (unsigned)y <= 9u) {
            const int rowb = (z * 10 + y) * 10;
            const int c0   = rowb + max(cx - 1, 0);
            const int c1   = rowb + min(cx + 1, 9);
            begv = cst[c0];
            lenv = cst[c1 + 1] - begv;
        }
    }
    const int rb0 = __shfl(begv, 0), rb1 = __shfl(begv, 1), rb2 = __shfl(begv, 2);
    const int rb3 = __shfl(begv, 3), rb4 = __shfl(begv, 4), rb5 = __shfl(begv, 5);
    const int rb6 = __shfl(begv, 6), rb7 = __shfl(begv, 7), rb8 = __shfl(begv, 8);
    const int ln0 = __shfl(lenv, 0), ln1 = __shfl(lenv, 1), ln2 = __shfl(lenv, 2);
    const int ln3 = __shfl(lenv, 3), ln4 = __shfl(lenv, 4), ln5 = __shfl(lenv, 5);
    const int ln6 = __shfl(lenv, 6), ln7 = __shfl(lenv, 7), ln8 = __shfl(lenv, 8);
    const int pf1 = ln0,       pf2 = pf1 + ln1, pf3 = pf2 + ln2;
    const int pf4 = pf3 + ln3, pf5 = pf4 + ln4, pf6 = pf5 + ln5;
    const int pf7 = pf6 + ln6, pf8 = pf7 + ln7, pf9 = pf8 + ln8;

    // ---- Phase A: scan candidates, compact nb hits into s_nb ----
    int nbcnt = 0;
    for (int base = 0; base < pf9; base += 64) {
        const int g = base + lane;
        int j = 0;
        if (g < pf9) j = rb8 + g - pf8;
        if (g < pf8) j = rb7 + g - pf7;
        if (g < pf7) j = rb6 + g - pf6;
        if (g < pf6) j = rb5 + g - pf5;
        if (g < pf5) j = rb4 + g - pf4;
        if (g < pf4) j = rb3 + g - pf3;
        if (g < pf3) j = rb2 + g - pf2;
        if (g < pf2) j = rb1 + g - pf1;
        if (g < pf1) j = rb0 + g;
        const float4 Q  = srt[j];
        const float dx = Q.x - P.x, dy = Q.y - P.y, dz = Q.z - P.z;
        const float d2 = dx * dx + dy * dy + dz * dz;
        const int   jw = (int)Q.w;
        const bool  nb = (g < pf9) && (d2 < R2) && ((jw & LEAFBIT) != 0);
        const unsigned long long m = __ballot(nb);
        if (nb) {
            const int pos = nbcnt + __popcll(m & ((1ull << lane) - 1ull));
            if (pos < NBCAP) s_nb[wid][pos] = jw & (LEAFBIT - 1);
        }
        nbcnt += __popcll(m);
    }
    const int cnt_nb = nbcnt;

    // ---- Phase B: cosine, 2 lanes per hit; survivors -> s_sv ----
    const int d    = lane & 31;
    const int half = lane >> 5;
    int csim = 0;
    const int nh = min(cnt_nb, NBCAP);
    for (int h0 = 0; h0 < nh; h0 += 32) {
        const int h = h0 + d;
        float dot = 0.0f, nj2 = 0.0f;
        int   jo  = 0;
        if (h < nh) {
            jo = s_nb[wid][h];
            const float4* ej4 = (const float4*)(embB + (size_t)jo * DIM) + half * 4;
            #pragma unroll
            for (int k = 0; k < 4; ++k) {
                const float4 v = ej4[k];
                const float4 a = *(const float4*)&s_ei[wid][16 * half + 4 * k];
                dot += a.x * v.x + a.y * v.y + a.z * v.z + a.w * v.w;
                nj2 += v.x * v.x + v.y * v.y + v.z * v.z + v.w * v.w;
            }
        }
        dot += __shfl_xor(dot, 32);
        nj2 += __shfl_xor(nj2, 32);
        bool surv = false;
        if (h < nh && half == 0) {
            const float rnj = 1.0f / fmaxf(sqrtf(nj2), 1e-8f);
            surv = (dot * rni * rnj) > 0.7f;
        }
        const unsigned long long m = __ballot(surv);
        if (surv) {
            const int pos = csim + __popcll(m & ((1ull << lane) - 1ull));
            s_sv[wid][pos] = jo;
        }
        csim += __popcll(m);
    }

    if (!((cnt_nb > 1) && (csim > 0))) return;   // out = emb done (wave-uniform)

    // ---- survivor mean: rows split across lane halves ----
    float msum = 0.0f;
    for (int v = half; v < csim; v += 2)
        msum += embB[(size_t)s_sv[wid][v] * DIM + d];
    msum += __shfl_xor(msum, 32);
    if (half == 0) s_mean[wid][d] = msum / (float)csim;

    // ---- MLP layer 1: k-range split across halves, shfl combine ----
    float a = (half == 0) ? b1[d] : 0.0f;
    #pragma unroll
    for (int k = 0; k < 16; ++k) {
        const int kk = half * 16 + k;
        a = fmaf(s_ei[wid][kk], W1[kk * DIM + d], a);
    }
    #pragma unroll
    for (int k = 0; k < 16; ++k) {
        const int kk = half * 16 + k;
        a = fmaf(s_mean[wid][kk], W1[(DIM + kk) * DIM + d], a);
    }
    a += __shfl_xor(a, 32);
    if (half == 0) s_h[wid][d] = fmaxf(a, 0.0f);

    // ---- MLP layer 2 ----
    float c = (half == 0) ? b2[d] : 0.0f;
    #pragma unroll
    for (int k = 0; k < 16; ++k) {
        const int kk = half * 16 + k;
        c = fmaf(s_h[wid][kk], W2[kk * DIM + d], c);
    }
    c += __shfl_xor(c, 32);
    if (half == 0)
        out[((size_t)b * NPTS + io) * DIM + d] = c;
}

extern "C" void kernel_launch(void* const* d_in, const int* in_sizes, int n_in,
                              void* d_out, int out_size, void* d_ws, size_t ws_size,
                              hipStream_t stream) {
    const float* points = (const float*)d_in[0];
    const float* emb    = (const float*)d_in[1];
    const int*   leaf   = (const int*)d_in[2];
    const float* W1     = (const float*)d_in[3];
    const float* b1     = (const float*)d_in[4];
    const float* W2     = (const float*)d_in[5];
    const float* b2     = (const float*)d_in[6];
    float*       outp   = (float*)d_out;
    int*         ws     = (int*)d_ws;

    build_cells<<<NB + COPYBLK, 1024, 0, stream>>>(points, leaf, emb, outp, ws);

    const int grid = (NB * NPTS) / NWAVES;                       // 3072
    refine<<<grid, BLOCK, 0, stream>>>(emb, W1, b1, W2, b2, ws, outp);
}